// Round 6
// baseline (480.222 us; speedup 1.0000x reference)
//
#include <hip/hip_runtime.h>

// B=2, S=2048, HID=1024, H=16, D=64, MAX_SEQ=2048.
// Storage: fp32 holding bf16-grid values. Internal compute: bf16.

typedef __attribute__((ext_vector_type(8))) short short8;
typedef __attribute__((ext_vector_type(4))) short short4v;
typedef __attribute__((ext_vector_type(4))) float f32x4;

__device__ __forceinline__ float bf2f(unsigned short u) {
  return __uint_as_float(((unsigned int)u) << 16);
}
__device__ __forceinline__ unsigned short f2bf(float f) {
  unsigned int u = __float_as_uint(f);
  u += 0x7fffu + ((u >> 16) & 1u);   // RNE
  return (unsigned short)(u >> 16);
}

#define GLL16(gp, lp) __builtin_amdgcn_global_load_lds( \
    (const __attribute__((address_space(1))) void*)(gp), \
    (__attribute__((address_space(3))) void*)(lp), 16, 0, 0)

#define MFMA16(a, b, c) __builtin_amdgcn_mfma_f32_16x16x32_bf16((a), (b), (c), 0, 0, 0)

// ---------------------------------------------------------------------------
// prep: fp32->bf16 converts + rope cos/sin table + rel transpose.
// ---------------------------------------------------------------------------
__global__ __launch_bounds__(256) void prep_kernel(
    const float* __restrict__ q, const float* __restrict__ k,
    const float* __restrict__ v,
    const float* __restrict__ wq, const float* __restrict__ wk,
    const float* __restrict__ wv, const float* __restrict__ wo,
    unsigned short* __restrict__ xq, unsigned short* __restrict__ xk,
    unsigned short* __restrict__ xv,
    unsigned short* __restrict__ wqb, unsigned short* __restrict__ wkb,
    unsigned short* __restrict__ wvb, unsigned short* __restrict__ wob,
    float* __restrict__ tab, float* __restrict__ relt,
    const float* __restrict__ rel)
{
  int tid = blockIdx.x * 256 + threadIdx.x;
  if (tid < 2097152) {          // converts
    const float* src; unsigned short* dst; size_t off;
    if (tid < 1572864) {
      int seg = tid / 524288, rc = tid - seg * 524288;
      src = seg == 0 ? q : (seg == 1 ? k : v);
      dst = seg == 0 ? xq : (seg == 1 ? xk : xv);
      off = (size_t)rc * 8;
    } else {
      int c2 = tid - 1572864;
      int seg = c2 / 131072, rc = c2 - seg * 131072;
      src = seg == 0 ? wq : (seg == 1 ? wk : (seg == 2 ? wv : wo));
      dst = seg == 0 ? wqb : (seg == 1 ? wkb : (seg == 2 ? wvb : wob));
      off = (size_t)rc * 8;
    }
    float4 f0 = ((const float4*)(src + off))[0];
    float4 f1 = ((const float4*)(src + off))[1];
    short8 o;
    o[0]=f2bf(f0.x); o[1]=f2bf(f0.y); o[2]=f2bf(f0.z); o[3]=f2bf(f0.w);
    o[4]=f2bf(f1.x); o[5]=f2bf(f1.y); o[6]=f2bf(f1.z); o[7]=f2bf(f1.w);
    *(short8*)(dst + off) = o;
  } else if (tid < 2162688) {   // rope table
    int u = tid - 2097152;
    int s = u >> 5, j = u & 31;
    float f = expf((float)j * -0.28782313662425575f);   // 10000^(-j/32)
    float sn, cs;
    sincosf((float)s * f, &sn, &cs);
    tab[s * 64 + j] = cs;
    tab[s * 64 + 32 + j] = sn;
  } else {                      // relt[h][d] = rel[d][h]
    int u = tid - 2162688;
    int hh = u >> 12, d = u & 4095;
    if (d < 4095) relt[hh * 4095 + d] = rel[d * 16 + hh];
  }
}

// ---------------------------------------------------------------------------
// 128x64-tile GEMM core, BK=32, 4 waves (2m x 2n of 64x32), GLL16 staging.
// SWAP=true: mfma(bf,af) -> D row(quad*4+r)=n, col(lid)=m.
// ---------------------------------------------------------------------------
template<bool SWAP>
__device__ __forceinline__ void core128x64(
    const unsigned short* gA, const unsigned short* gB,
    unsigned short* As, unsigned short* Bs,
    f32x4 (&acc)[4][2], int t, int wm, int wn, int lid, int quad)
{
  for (int k0 = 0; k0 < 1024; k0 += 32) {
    __syncthreads();
    GLL16(gA + k0,         As + t * 8);
    GLL16(gA + 65536 + k0, As + 2048 + t * 8);   // rows 64..127
    GLL16(gB + k0,         Bs + t * 8);
    __syncthreads();
    short8 af[4], bf[2];
#pragma unroll
    for (int i = 0; i < 4; i++)
      af[i] = *(const short8*)(As + (wm + i * 16 + lid) * 32 + quad * 8);
#pragma unroll
    for (int j = 0; j < 2; j++)
      bf[j] = *(const short8*)(Bs + (wn + j * 16 + lid) * 32 + quad * 8);
#pragma unroll
    for (int i = 0; i < 4; i++)
#pragma unroll
      for (int j = 0; j < 2; j++)
        acc[i][j] = SWAP ? MFMA16(bf[j], af[i], acc[i][j])
                         : MFMA16(af[i], bf[j], acc[i][j]);
  }
}

// QKV projections: z=0 Q, z=1 K (scatter [B,H,S,D]); z=2 V (scatter [B,H,D,S]).
__global__ __launch_bounds__(256) void gemm_qkv(
    const unsigned short* __restrict__ Xq, const unsigned short* __restrict__ Xk,
    const unsigned short* __restrict__ Xv,
    const unsigned short* __restrict__ Wq, const unsigned short* __restrict__ Wk,
    const unsigned short* __restrict__ Wv,
    const float* __restrict__ bq, const float* __restrict__ bk,
    const float* __restrict__ bv,
    unsigned short* __restrict__ Qr, unsigned short* __restrict__ Kr,
    unsigned short* __restrict__ Vtr)
{
  __shared__ unsigned short As[128 * 32];
  __shared__ unsigned short Bs[64 * 32];
  const int z = blockIdx.z;
  const unsigned short* X = z == 0 ? Xq : (z == 1 ? Xk : Xv);
  const unsigned short* W = z == 0 ? Wq : (z == 1 ? Wk : Wv);
  const float* Bi = z == 0 ? bq : (z == 1 ? bk : bv);
  unsigned short* O = z == 0 ? Qr : (z == 1 ? Kr : Vtr);

  const int t    = threadIdx.x;
  const int lane = t & 63;
  const int lid  = lane & 15;
  const int quad = lane >> 4;
  const int w    = t >> 6;
  const int wm   = (w >> 1) * 64;
  const int wn   = (w & 1) * 32;
  const int m0   = blockIdx.y * 128;
  const int n0   = blockIdx.x * 64;

  const unsigned short* gA = X + (size_t)(m0 + (t >> 2)) * 1024 + (t & 3) * 8;
  const unsigned short* gB = W + (size_t)(n0 + (t >> 2)) * 1024 + (t & 3) * 8;

  f32x4 acc[4][2];
#pragma unroll
  for (int i = 0; i < 4; i++)
#pragma unroll
    for (int j = 0; j < 2; j++) acc[i][j] = (f32x4){0.f, 0.f, 0.f, 0.f};

  if (z == 2) core128x64<false>(gA, gB, As, Bs, acc, t, wm, wn, lid, quad);
  else        core128x64<true >(gA, gB, As, Bs, acc, t, wm, wn, lid, quad);

  if (z < 2) {   // swapped: row->n(d), col->m(s); short4 along d
#pragma unroll
    for (int jn = 0; jn < 2; jn++) {
      int nn = n0 + wn + jn * 16 + quad * 4;
      int hh = nn >> 6, d0 = nn & 63;
      float4 b4 = *(const float4*)(Bi + nn);
#pragma unroll
      for (int im = 0; im < 4; im++) {
        int m = m0 + wm + im * 16 + lid;
        int bb = m >> 11, s = m & 2047;
        short4v pk;
        pk[0] = (short)f2bf(acc[im][jn][0] + b4.x);
        pk[1] = (short)f2bf(acc[im][jn][1] + b4.y);
        pk[2] = (short)f2bf(acc[im][jn][2] + b4.z);
        pk[3] = (short)f2bf(acc[im][jn][3] + b4.w);
        *(short4v*)(O + ((size_t)((bb * 16 + hh) * 2048 + s)) * 64 + d0) = pk;
      }
    }
  } else {       // unswapped: row->m(s), col->n(d); short4 along s into [B,H,D,S]
#pragma unroll
    for (int j = 0; j < 2; j++) {
      int n = n0 + wn + j * 16 + lid;
      int hh = n >> 6, d = n & 63;
      float bvv = Bi[n];
#pragma unroll
      for (int i = 0; i < 4; i++) {
        int mr = m0 + wm + i * 16 + quad * 4;
        int bb = mr >> 11, s0 = mr & 2047;
        short4v pk;
        pk[0] = (short)f2bf(acc[i][j][0] + bvv);
        pk[1] = (short)f2bf(acc[i][j][1] + bvv);
        pk[2] = (short)f2bf(acc[i][j][2] + bvv);
        pk[3] = (short)f2bf(acc[i][j][3] + bvv);
        *(short4v*)(O + ((size_t)((bb * 16 + hh) * 64 + d)) * 2048 + s0) = pk;
      }
    }
  }
}

// ---------------------------------------------------------------------------
// Output projection: 64x64 tiles, 1024 blocks. fp32 float4 output.
// ---------------------------------------------------------------------------
__global__ __launch_bounds__(256) void gemm_out(
    const unsigned short* __restrict__ X, const unsigned short* __restrict__ W,
    const float* __restrict__ Bi, float* __restrict__ O)
{
  __shared__ unsigned short As[64 * 32];
  __shared__ unsigned short Bs[64 * 32];
  const int t    = threadIdx.x;
  const int lane = t & 63;
  const int lid  = lane & 15;
  const int quad = lane >> 4;
  const int w    = t >> 6;
  const int wm   = (w >> 1) * 32;
  const int wn   = (w & 1) * 32;
  const int m0   = blockIdx.y * 64;
  const int n0   = blockIdx.x * 64;

  const unsigned short* gA = X + (size_t)(m0 + (t >> 2)) * 1024 + (t & 3) * 8;
  const unsigned short* gB = W + (size_t)(n0 + (t >> 2)) * 1024 + (t & 3) * 8;

  f32x4 acc[2][2];
#pragma unroll
  for (int i = 0; i < 2; i++)
#pragma unroll
    for (int j = 0; j < 2; j++) acc[i][j] = (f32x4){0.f, 0.f, 0.f, 0.f};

  for (int k0 = 0; k0 < 1024; k0 += 32) {
    __syncthreads();
    GLL16(gA + k0, As + t * 8);
    GLL16(gB + k0, Bs + t * 8);
    __syncthreads();
    short8 af[2], bf[2];
#pragma unroll
    for (int i = 0; i < 2; i++)
      af[i] = *(const short8*)(As + (wm + i * 16 + lid) * 32 + quad * 8);
#pragma unroll
    for (int j = 0; j < 2; j++)
      bf[j] = *(const short8*)(Bs + (wn + j * 16 + lid) * 32 + quad * 8);
#pragma unroll
    for (int i = 0; i < 2; i++)
#pragma unroll
      for (int j = 0; j < 2; j++)
        acc[i][j] = MFMA16(bf[j], af[i], acc[i][j]);   // swapped
  }
#pragma unroll
  for (int jn = 0; jn < 2; jn++) {
    int nn = n0 + wn + jn * 16 + quad * 4;
    float4 b4 = *(const float4*)(Bi + nn);
#pragma unroll
    for (int im = 0; im < 2; im++) {
      int m = m0 + wm + im * 16 + lid;
      float4 ov;
      ov.x = acc[im][jn][0] + b4.x;
      ov.y = acc[im][jn][1] + b4.y;
      ov.z = acc[im][jn][2] + b4.z;
      ov.w = acc[im][jn][3] + b4.w;
      *(float4*)(O + (size_t)m * 1024 + nn) = ov;
    }
  }
}

// ---------------------------------------------------------------------------
// RoPE apply (reference variant), in-place on bf16 [B,H,S,64].
// ---------------------------------------------------------------------------
__global__ __launch_bounds__(256) void rope_kernel(unsigned short* __restrict__ Q,
                                                   unsigned short* __restrict__ Kp,
                                                   const float* __restrict__ tab)
{
  int row = blockIdx.x * 256 + threadIdx.x;
  unsigned short* P = ((blockIdx.y == 0) ? Q : Kp) + (size_t)row * 64;
  const float* tr = tab + (size_t)(row & 2047) * 64;

  short8 xv[8];
#pragma unroll
  for (int c = 0; c < 8; c++) xv[c] = *(const short8*)(P + c * 8);
#define XE(i) bf2f((unsigned short)xv[(i) >> 3][(i) & 7])
  short8 ov[8];
#pragma unroll
  for (int j = 0; j < 32; j++) {
    float cs = tr[j], sn = tr[32 + j];
    float yl = XE(j) * cs      - XE(2 * j + 1) * sn;
    float yh = XE(j + 32) * cs + XE(2 * j)     * sn;
    ov[j >> 3][j & 7]       = (short)f2bf(yl);
    ov[(j >> 3) + 4][j & 7] = (short)f2bf(yh);
  }
#undef XE
#pragma unroll
  for (int c = 0; c < 8; c++) *(short8*)(P + c * 8) = ov[c];
}

// ---------------------------------------------------------------------------
// Split-K flash attention (exp-direct: partials combine linearly).
// Block = 1 wave = (bh, 16-row strip p, k-segment s). Segments of 1024 k:
// strips 0..63 have 1 seg, 64..127 have 2 -> 192 segs/bh, 6144 blocks
// (24 waves/CU vs round-5's 8). Each seg <= 16 iters. Heavy-first.
// Partial O (fp32 16x64) + l (16) per seg -> attn_reduce combines.
// ---------------------------------------------------------------------------
__global__ __launch_bounds__(64, 4) void attn_partial(
    const unsigned short* __restrict__ Q, const unsigned short* __restrict__ Kg,
    const unsigned short* __restrict__ Vt, const float* __restrict__ relt,
    float* __restrict__ Opart, float* __restrict__ Lpart)
{
  __shared__ unsigned short Ps[16 * 72];

  const int lane = threadIdx.x;
  const int lid  = lane & 15;
  const int quad = lane >> 4;
  const int er   = 191 - blockIdx.x;    // heavy-first
  const int bh   = blockIdx.y;
  const int h    = bh & 15;
  int p, s;
  if (er < 64) { p = er; s = 0; }
  else { int u = er - 64; p = 64 + (u >> 1); s = u & 1; }
  const int slot = bh * 192 + er;
  const int q0   = 16 * p;
  const int k_lo = s << 10;
  const int k_hi = min(q0 + 16, (s + 1) << 10);

  const unsigned short* Qb = Q  + (size_t)bh * (2048 * 64);
  const unsigned short* Kb = Kg + (size_t)bh * (2048 * 64);
  const unsigned short* Vb = Vt + (size_t)bh * (64 * 2048);
  const float* relh = relt + h * 4095 + 2047;

  short8 aq[2];
  {
    const unsigned short* qp = Qb + (size_t)(q0 + lid) * 64;
    aq[0] = *(const short8*)(qp + quad * 8);
    aq[1] = *(const short8*)(qp + 32 + quad * 8);
  }

  f32x4 acc[4];
  float l[4] = {0.f, 0.f, 0.f, 0.f};
#pragma unroll
  for (int dj = 0; dj < 4; dj++) acc[dj] = (f32x4){0.f, 0.f, 0.f, 0.f};

  const unsigned short* kr = Kb + (size_t)lid * 64 + quad * 8;
  const unsigned short* vr = Vb + (size_t)lid * 2048 + quad * 8;

  short8 ck[4][2], nk[4][2], cv[4][2];
  auto loadK = [&](short8 (&fk)[4][2], int k0) {
#pragma unroll
    for (int x = 0; x < 4; x++) {
      const unsigned short* kp = kr + (size_t)(k0 + x * 16) * 64;
      fk[x][0] = *(const short8*)kp;
      fk[x][1] = *(const short8*)(kp + 32);
    }
  };
  auto loadV = [&](short8 (&fv)[4][2], int k0) {
#pragma unroll
    for (int x = 0; x < 4; x++) {
      const unsigned short* vp = vr + (size_t)(x * 16) * 2048 + k0;
      fv[x][0] = *(const short8*)vp;
      fv[x][1] = *(const short8*)(vp + 32);
    }
  };
  const int qr0 = q0 + quad * 4;
  auto proc = [&](int k0, const short8 (&fk)[4][2], const short8 (&fv)[4][2]) {
    f32x4 s4[4];
#pragma unroll
    for (int jt = 0; jt < 4; jt++) {
      s4[jt] = (f32x4){0.f, 0.f, 0.f, 0.f};
      s4[jt] = MFMA16(aq[0], fk[jt][0], s4[jt]);
      s4[jt] = MFMA16(aq[1], fk[jt][1], s4[jt]);
    }
#pragma unroll
    for (int jt = 0; jt < 4; jt++) {
      int kb = k0 + jt * 16 + lid;
      const float* rp = relh + (qr0 - kb);
#pragma unroll
      for (int r = 0; r < 4; r++) {
        float sc = fmaf(s4[jt][r], 0.125f, rp[r]);
        float pv = (kb > qr0 + r) ? 0.f : __expf(sc);
        l[r] += pv;
        Ps[(quad * 4 + r) * 72 + jt * 16 + lid] = f2bf(pv);
      }
    }
    short8 ap0 = *(const short8*)(Ps + lid * 72 + quad * 8);
    short8 ap1 = *(const short8*)(Ps + lid * 72 + 32 + quad * 8);
#pragma unroll
    for (int dj = 0; dj < 4; dj++) {
      acc[dj] = MFMA16(ap0, fv[dj][0], acc[dj]);
      acc[dj] = MFMA16(ap1, fv[dj][1], acc[dj]);
    }
  };

  int k0 = k_lo;
  loadK(ck, k0);
  while (true) {
    int k1 = k0 + 64;
    if (k1 < k_hi) loadK(nk, k1);
    loadV(cv, k0);
    proc(k0, ck, cv);
    if (k1 >= k_hi) break;
    k0 = k1; k1 = k0 + 64;
    if (k1 < k_hi) loadK(ck, k1);
    loadV(cv, k0);
    proc(k0, nk, cv);
    if (k1 >= k_hi) break;
    k0 = k1;
  }

  // reduce l across the 16 lanes of each quad; store fp32 partials
#pragma unroll
  for (int d2 = 1; d2 < 16; d2 <<= 1)
#pragma unroll
    for (int r = 0; r < 4; r++) l[r] += __shfl_xor(l[r], d2);

  float* Ob = Opart + (size_t)slot * 1024;
#pragma unroll
  for (int dj = 0; dj < 4; dj++)
#pragma unroll
    for (int r = 0; r < 4; r++)
      Ob[(quad * 4 + r) * 64 + dj * 16 + lid] = acc[dj][r];
  if (lid == 0) {
#pragma unroll
    for (int r = 0; r < 4; r++) Lpart[slot * 16 + quad * 4 + r] = l[r];
  }
}

// ---------------------------------------------------------------------------
// Combine <=2 segments per strip, normalize, clip, write bf16 AO [B,S,HID].
// Grid (128 strips, 32 bh) x 256 threads; thread = (row=t>>4, 4 d-elems).
// ---------------------------------------------------------------------------
__global__ __launch_bounds__(256) void attn_reduce(
    const float* __restrict__ Opart, const float* __restrict__ Lpart,
    unsigned short* __restrict__ AO)
{
  const int p  = blockIdx.x;
  const int bh = blockIdx.y;
  const int t  = threadIdx.x;
  const int er0  = (p < 64) ? p : 64 + ((p - 64) << 1);
  const int slot = bh * 192 + er0;
  const int row = t >> 4, d0 = (t & 15) * 4;

  const float* O0 = Opart + (size_t)slot * 1024 + row * 64 + d0;
  float4 a = *(const float4*)O0;
  float l = Lpart[slot * 16 + row];
  if (p >= 64) {
    float4 a2 = *(const float4*)(O0 + 1024);
    a.x += a2.x; a.y += a2.y; a.z += a2.z; a.w += a2.w;
    l += Lpart[(slot + 1) * 16 + row];
  }
  float rcp = 1.f / l;
  short4v pk;
  pk[0] = (short)f2bf(fminf(fmaxf(a.x * rcp, -30.f), 30.f));
  pk[1] = (short)f2bf(fminf(fmaxf(a.y * rcp, -30.f), 30.f));
  pk[2] = (short)f2bf(fminf(fmaxf(a.z * rcp, -30.f), 30.f));
  pk[3] = (short)f2bf(fminf(fmaxf(a.w * rcp, -30.f), 30.f));
  int qrow = 16 * p + row;
  *(short4v*)(AO + ((size_t)(bh >> 4) * 2048 + qrow) * 1024 + (bh & 15) * 64 + d0) = pk;
}

// ---------------------------------------------------------------------------
extern "C" void kernel_launch(void* const* d_in, const int* in_sizes, int n_in,
                              void* d_out, int out_size, void* d_ws, size_t ws_size,
                              hipStream_t stream) {
  const float* query  = (const float*)d_in[0];
  const float* key_in = (const float*)d_in[1];
  const float* value  = (const float*)d_in[2];
  const float* wq = (const float*)d_in[4];
  const float* bq = (const float*)d_in[5];
  const float* wk = (const float*)d_in[6];
  const float* bk = (const float*)d_in[7];
  const float* wv = (const float*)d_in[8];
  const float* bv = (const float*)d_in[9];
  const float* wo = (const float*)d_in[10];
  const float* bo = (const float*)d_in[11];
  const float* rel = (const float*)d_in[12];

  // ws layout; aliases are strictly after the last reader in stream order:
  //   Opart/Lpart overwrite Xq,Xk,Xv,Wq (dead after gemm_qkv);
  //   AO overwrites Qr (dead after attn_partial); Wo stays live for gemm_out.
  char* ws = (char*)d_ws;
  unsigned short* Xq = (unsigned short*)(ws);                 // 8.39 MB
  unsigned short* Xk = (unsigned short*)(ws + 8388608);
  unsigned short* Xv = (unsigned short*)(ws + 16777216);
  unsigned short* Wq = (unsigned short*)(ws + 25165824);      // 2.10 MB each
  unsigned short* Wk = (unsigned short*)(ws + 27262976);
  unsigned short* Wv = (unsigned short*)(ws + 29360128);
  unsigned short* Wo = (unsigned short*)(ws + 31457280);
  unsigned short* Qr  = (unsigned short*)(ws + 33554432);     // 8.39 MB
  unsigned short* Kr  = (unsigned short*)(ws + 41943040);
  unsigned short* Vtr = (unsigned short*)(ws + 50331648);     // [B,H,D,S]
  float* Opart = (float*)ws;                                  // 6144*4KB = 24MB
  float* Lpart = (float*)(ws + 25165824);                     // 384KB (over Wq)
  unsigned short* AOp = Qr;            // alias: Qr dead after attn_partial
  // tab/relt live in d_out scratch (overwritten by gemm_out at the end)
  float* out  = (float*)d_out;
  float* tab  = out;                   // 131072 floats
  float* relt = out + 131072;          // 65520 floats

  dim3 blk(256);
  prep_kernel<<<dim3(8704), blk, 0, stream>>>(
      query, key_in, value, wq, wk, wv, wo,
      Xq, Xk, Xv, Wq, Wk, Wv, Wo, tab, relt, rel);
  gemm_qkv<<<dim3(16, 32, 3), blk, 0, stream>>>(
      Xq, Xk, Xv, Wq, Wk, Wv, bq, bk, bv, Qr, Kr, Vtr);
  rope_kernel<<<dim3(256, 2), blk, 0, stream>>>(Qr, Kr, tab);
  attn_partial<<<dim3(192, 32), dim3(64), 0, stream>>>(Qr, Kr, Vtr, relt,
                                                       Opart, Lpart);
  attn_reduce<<<dim3(128, 32), blk, 0, stream>>>(Opart, Lpart, AOp);
  gemm_out<<<dim3(16, 64), blk, 0, stream>>>(AOp, Wo, bo, out);
}

// Round 7
// 406.122 us; speedup vs baseline: 1.1825x; 1.1825x over previous
//
#include <hip/hip_runtime.h>

// B=2, S=2048, HID=1024, H=16, D=64, MAX_SEQ=2048.
// Storage: fp32 holding bf16-grid values. Internal compute: bf16.

typedef __attribute__((ext_vector_type(8))) short short8;
typedef __attribute__((ext_vector_type(4))) short short4v;
typedef __attribute__((ext_vector_type(4))) float f32x4;

__device__ __forceinline__ float bf2f(unsigned short u) {
  return __uint_as_float(((unsigned int)u) << 16);
}
__device__ __forceinline__ unsigned short f2bf(float f) {
  unsigned int u = __float_as_uint(f);
  u += 0x7fffu + ((u >> 16) & 1u);   // RNE
  return (unsigned short)(u >> 16);
}

#define GLL16(gp, lp) __builtin_amdgcn_global_load_lds( \
    (const __attribute__((address_space(1))) void*)(gp), \
    (__attribute__((address_space(3))) void*)(lp), 16, 0, 0)

#define MFMA16(a, b, c)  __builtin_amdgcn_mfma_f32_16x16x32_bf16((a), (b), (c), 0, 0, 0)
#define MFMAK16(a, b, c) __builtin_amdgcn_mfma_f32_16x16x16bf16_1k((a), (b), (c), 0, 0, 0)

// ---------------------------------------------------------------------------
// prep: fp32->bf16 converts + rope cos/sin table + rel transpose.
// ---------------------------------------------------------------------------
__global__ __launch_bounds__(256) void prep_kernel(
    const float* __restrict__ q, const float* __restrict__ k,
    const float* __restrict__ v,
    const float* __restrict__ wq, const float* __restrict__ wk,
    const float* __restrict__ wv, const float* __restrict__ wo,
    unsigned short* __restrict__ xq, unsigned short* __restrict__ xk,
    unsigned short* __restrict__ xv,
    unsigned short* __restrict__ wqb, unsigned short* __restrict__ wkb,
    unsigned short* __restrict__ wvb, unsigned short* __restrict__ wob,
    float* __restrict__ tab, float* __restrict__ relt,
    const float* __restrict__ rel)
{
  int tid = blockIdx.x * 256 + threadIdx.x;
  if (tid < 2097152) {          // converts
    const float* src; unsigned short* dst; size_t off;
    if (tid < 1572864) {
      int seg = tid / 524288, rc = tid - seg * 524288;
      src = seg == 0 ? q : (seg == 1 ? k : v);
      dst = seg == 0 ? xq : (seg == 1 ? xk : xv);
      off = (size_t)rc * 8;
    } else {
      int c2 = tid - 1572864;
      int seg = c2 / 131072, rc = c2 - seg * 131072;
      src = seg == 0 ? wq : (seg == 1 ? wk : (seg == 2 ? wv : wo));
      dst = seg == 0 ? wqb : (seg == 1 ? wkb : (seg == 2 ? wvb : wob));
      off = (size_t)rc * 8;
    }
    float4 f0 = ((const float4*)(src + off))[0];
    float4 f1 = ((const float4*)(src + off))[1];
    short8 o;
    o[0]=f2bf(f0.x); o[1]=f2bf(f0.y); o[2]=f2bf(f0.z); o[3]=f2bf(f0.w);
    o[4]=f2bf(f1.x); o[5]=f2bf(f1.y); o[6]=f2bf(f1.z); o[7]=f2bf(f1.w);
    *(short8*)(dst + off) = o;
  } else if (tid < 2162688) {   // rope table
    int u = tid - 2097152;
    int s = u >> 5, j = u & 31;
    float f = expf((float)j * -0.28782313662425575f);   // 10000^(-j/32)
    float sn, cs;
    sincosf((float)s * f, &sn, &cs);
    tab[s * 64 + j] = cs;
    tab[s * 64 + 32 + j] = sn;
  } else {                      // relt[h][d] = rel[d][h]
    int u = tid - 2162688;
    int hh = u >> 12, d = u & 4095;
    if (d < 4095) relt[hh * 4095 + d] = rel[d * 16 + hh];
  }
}

// ---------------------------------------------------------------------------
// 128x64-tile GEMM core, BK=32, 4 waves (2m x 2n of 64x32), GLL16 staging.
// SWAP=true: mfma(bf,af) -> D row(quad*4+r)=n, col(lid)=m.
// ---------------------------------------------------------------------------
template<bool SWAP>
__device__ __forceinline__ void core128x64(
    const unsigned short* gA, const unsigned short* gB,
    unsigned short* As, unsigned short* Bs,
    f32x4 (&acc)[4][2], int t, int wm, int wn, int lid, int quad)
{
  for (int k0 = 0; k0 < 1024; k0 += 32) {
    __syncthreads();
    GLL16(gA + k0,         As + t * 8);
    GLL16(gA + 65536 + k0, As + 2048 + t * 8);   // rows 64..127
    GLL16(gB + k0,         Bs + t * 8);
    __syncthreads();
    short8 af[4], bf[2];
#pragma unroll
    for (int i = 0; i < 4; i++)
      af[i] = *(const short8*)(As + (wm + i * 16 + lid) * 32 + quad * 8);
#pragma unroll
    for (int j = 0; j < 2; j++)
      bf[j] = *(const short8*)(Bs + (wn + j * 16 + lid) * 32 + quad * 8);
#pragma unroll
    for (int i = 0; i < 4; i++)
#pragma unroll
      for (int j = 0; j < 2; j++)
        acc[i][j] = SWAP ? MFMA16(bf[j], af[i], acc[i][j])
                         : MFMA16(af[i], bf[j], acc[i][j]);
  }
}

// QKV projections: z=0 Q, z=1 K (scatter [B,H,S,D]); z=2 V (scatter [B,H,D,S]).
__global__ __launch_bounds__(256) void gemm_qkv(
    const unsigned short* __restrict__ Xq, const unsigned short* __restrict__ Xk,
    const unsigned short* __restrict__ Xv,
    const unsigned short* __restrict__ Wq, const unsigned short* __restrict__ Wk,
    const unsigned short* __restrict__ Wv,
    const float* __restrict__ bq, const float* __restrict__ bk,
    const float* __restrict__ bv,
    unsigned short* __restrict__ Qr, unsigned short* __restrict__ Kr,
    unsigned short* __restrict__ Vtr)
{
  __shared__ unsigned short As[128 * 32];
  __shared__ unsigned short Bs[64 * 32];
  const int z = blockIdx.z;
  const unsigned short* X = z == 0 ? Xq : (z == 1 ? Xk : Xv);
  const unsigned short* W = z == 0 ? Wq : (z == 1 ? Wk : Wv);
  const float* Bi = z == 0 ? bq : (z == 1 ? bk : bv);
  unsigned short* O = z == 0 ? Qr : (z == 1 ? Kr : Vtr);

  const int t    = threadIdx.x;
  const int lane = t & 63;
  const int lid  = lane & 15;
  const int quad = lane >> 4;
  const int w    = t >> 6;
  const int wm   = (w >> 1) * 64;
  const int wn   = (w & 1) * 32;
  const int m0   = blockIdx.y * 128;
  const int n0   = blockIdx.x * 64;

  const unsigned short* gA = X + (size_t)(m0 + (t >> 2)) * 1024 + (t & 3) * 8;
  const unsigned short* gB = W + (size_t)(n0 + (t >> 2)) * 1024 + (t & 3) * 8;

  f32x4 acc[4][2];
#pragma unroll
  for (int i = 0; i < 4; i++)
#pragma unroll
    for (int j = 0; j < 2; j++) acc[i][j] = (f32x4){0.f, 0.f, 0.f, 0.f};

  if (z == 2) core128x64<false>(gA, gB, As, Bs, acc, t, wm, wn, lid, quad);
  else        core128x64<true >(gA, gB, As, Bs, acc, t, wm, wn, lid, quad);

  if (z < 2) {   // swapped: row->n(d), col->m(s); short4 along d
#pragma unroll
    for (int jn = 0; jn < 2; jn++) {
      int nn = n0 + wn + jn * 16 + quad * 4;
      int hh = nn >> 6, d0 = nn & 63;
      float4 b4 = *(const float4*)(Bi + nn);
#pragma unroll
      for (int im = 0; im < 4; im++) {
        int m = m0 + wm + im * 16 + lid;
        int bb = m >> 11, s = m & 2047;
        short4v pk;
        pk[0] = (short)f2bf(acc[im][jn][0] + b4.x);
        pk[1] = (short)f2bf(acc[im][jn][1] + b4.y);
        pk[2] = (short)f2bf(acc[im][jn][2] + b4.z);
        pk[3] = (short)f2bf(acc[im][jn][3] + b4.w);
        *(short4v*)(O + ((size_t)((bb * 16 + hh) * 2048 + s)) * 64 + d0) = pk;
      }
    }
  } else {       // unswapped: row->m(s), col->n(d); short4 along s into [B,H,D,S]
#pragma unroll
    for (int j = 0; j < 2; j++) {
      int n = n0 + wn + j * 16 + lid;
      int hh = n >> 6, d = n & 63;
      float bvv = Bi[n];
#pragma unroll
      for (int i = 0; i < 4; i++) {
        int mr = m0 + wm + i * 16 + quad * 4;
        int bb = mr >> 11, s0 = mr & 2047;
        short4v pk;
        pk[0] = (short)f2bf(acc[i][j][0] + bvv);
        pk[1] = (short)f2bf(acc[i][j][1] + bvv);
        pk[2] = (short)f2bf(acc[i][j][2] + bvv);
        pk[3] = (short)f2bf(acc[i][j][3] + bvv);
        *(short4v*)(O + ((size_t)((bb * 16 + hh) * 64 + d)) * 2048 + s0) = pk;
      }
    }
  }
}

// ---------------------------------------------------------------------------
// Output projection: 64x64 tiles, 1024 blocks. fp32 float4 output.
// ---------------------------------------------------------------------------
__global__ __launch_bounds__(256) void gemm_out(
    const unsigned short* __restrict__ X, const unsigned short* __restrict__ W,
    const float* __restrict__ Bi, float* __restrict__ O)
{
  __shared__ unsigned short As[64 * 32];
  __shared__ unsigned short Bs[64 * 32];
  const int t    = threadIdx.x;
  const int lane = t & 63;
  const int lid  = lane & 15;
  const int quad = lane >> 4;
  const int w    = t >> 6;
  const int wm   = (w >> 1) * 32;
  const int wn   = (w & 1) * 32;
  const int m0   = blockIdx.y * 64;
  const int n0   = blockIdx.x * 64;

  const unsigned short* gA = X + (size_t)(m0 + (t >> 2)) * 1024 + (t & 3) * 8;
  const unsigned short* gB = W + (size_t)(n0 + (t >> 2)) * 1024 + (t & 3) * 8;

  f32x4 acc[2][2];
#pragma unroll
  for (int i = 0; i < 2; i++)
#pragma unroll
    for (int j = 0; j < 2; j++) acc[i][j] = (f32x4){0.f, 0.f, 0.f, 0.f};

  for (int k0 = 0; k0 < 1024; k0 += 32) {
    __syncthreads();
    GLL16(gA + k0, As + t * 8);
    GLL16(gB + k0, Bs + t * 8);
    __syncthreads();
    short8 af[2], bf[2];
#pragma unroll
    for (int i = 0; i < 2; i++)
      af[i] = *(const short8*)(As + (wm + i * 16 + lid) * 32 + quad * 8);
#pragma unroll
    for (int j = 0; j < 2; j++)
      bf[j] = *(const short8*)(Bs + (wn + j * 16 + lid) * 32 + quad * 8);
#pragma unroll
    for (int i = 0; i < 2; i++)
#pragma unroll
      for (int j = 0; j < 2; j++)
        acc[i][j] = MFMA16(bf[j], af[i], acc[i][j]);   // swapped
  }
#pragma unroll
  for (int jn = 0; jn < 2; jn++) {
    int nn = n0 + wn + jn * 16 + quad * 4;
    float4 b4 = *(const float4*)(Bi + nn);
#pragma unroll
    for (int im = 0; im < 2; im++) {
      int m = m0 + wm + im * 16 + lid;
      float4 ov;
      ov.x = acc[im][jn][0] + b4.x;
      ov.y = acc[im][jn][1] + b4.y;
      ov.z = acc[im][jn][2] + b4.z;
      ov.w = acc[im][jn][3] + b4.w;
      *(float4*)(O + (size_t)m * 1024 + nn) = ov;
    }
  }
}

// ---------------------------------------------------------------------------
// RoPE apply (reference variant), in-place on bf16 [B,H,S,64].
// ---------------------------------------------------------------------------
__global__ __launch_bounds__(256) void rope_kernel(unsigned short* __restrict__ Q,
                                                   unsigned short* __restrict__ Kp,
                                                   const float* __restrict__ tab)
{
  int row = blockIdx.x * 256 + threadIdx.x;
  unsigned short* P = ((blockIdx.y == 0) ? Q : Kp) + (size_t)row * 64;
  const float* tr = tab + (size_t)(row & 2047) * 64;

  short8 xv[8];
#pragma unroll
  for (int c = 0; c < 8; c++) xv[c] = *(const short8*)(P + c * 8);
#define XE(i) bf2f((unsigned short)xv[(i) >> 3][(i) & 7])
  short8 ov[8];
#pragma unroll
  for (int j = 0; j < 32; j++) {
    float cs = tr[j], sn = tr[32 + j];
    float yl = XE(j) * cs      - XE(2 * j + 1) * sn;
    float yh = XE(j + 32) * cs + XE(2 * j)     * sn;
    ov[j >> 3][j & 7]       = (short)f2bf(yl);
    ov[(j >> 3) + 4][j & 7] = (short)f2bf(yh);
  }
#undef XE
#pragma unroll
  for (int c = 0; c < 8; c++) *(short8*)(P + c * 8) = ov[c];
}

// ---------------------------------------------------------------------------
// LDS-free flash attention. Paired 16-row strips (perfect balance, r5 grid:
// 2048 blocks x 1 wave), exp-direct softmax, NO LDS / NO in-loop shuffles.
// Trick: S^T = mfma(K-frag, Q-frag) lands in C-layout (k=quad*4+r, q=lid),
// which IS the B-operand layout of mfma_16x16x16bf16; after in-register
// bias+mask+exp, P feeds PV directly. A-operand = V^T short4 from [B,H,D,S].
// Result = O^T in C-layout (d=dj*16+quad*4+r, q=lid) -> short4 stores.
// ---------------------------------------------------------------------------
__global__ __launch_bounds__(64, 2) void attn_kernel(
    const unsigned short* __restrict__ Q, const unsigned short* __restrict__ Kg,
    const unsigned short* __restrict__ Vt, const float* __restrict__ relt,
    unsigned short* __restrict__ AO)
{
  const int lane = threadIdx.x;
  const int lid  = lane & 15;
  const int quad = lane >> 4;
  const int jid  = blockIdx.x;          // 0..2047
  const int bh   = jid >> 6;
  const int p    = jid & 63;
  const int h    = bh & 15;
  const int qA   = 2032 - 16 * p;       // heavy strip rows [qA, qA+16)
  const int qB   = 16 * p;              // light strip rows [qB, qB+16)
  const int kendA = qA + 16, kendB = qB + 16;

  const unsigned short* Qb = Q  + (size_t)bh * (2048 * 64);
  const unsigned short* Kb = Kg + (size_t)bh * (2048 * 64);
  const unsigned short* Vb = Vt + (size_t)bh * (64 * 2048);
  const float* relh = relt + h * 4095 + 2047;
  unsigned short* AOb = AO + (size_t)(bh >> 4) * (2048 * 1024) + h * 64;

  // Q as B-operand frags (n=lid -> q, k=quad*8+j -> d)
  short8 aqA[2], aqB[2];
  {
    const unsigned short* qp = Qb + (size_t)(qA + lid) * 64;
    aqA[0] = *(const short8*)(qp + quad * 8);
    aqA[1] = *(const short8*)(qp + 32 + quad * 8);
    qp = Qb + (size_t)(qB + lid) * 64;
    aqB[0] = *(const short8*)(qp + quad * 8);
    aqB[1] = *(const short8*)(qp + 32 + quad * 8);
  }

  f32x4 accA[4], accB[4];               // O^T C-layout per 16-d block
  float lA = 0.f, lB = 0.f;             // per-lane partial denominators
#pragma unroll
  for (int dj = 0; dj < 4; dj++) {
    accA[dj] = (f32x4){0.f, 0.f, 0.f, 0.f};
    accB[dj] = (f32x4){0.f, 0.f, 0.f, 0.f};
  }

  const unsigned short* kr = Kb + (size_t)lid * 64 + quad * 8;
  const unsigned short* vr = Vb + (size_t)lid * 2048 + quad * 4;   // V^T A-frag base

  short8 ck[4][2], nk[4][2];
  short4v cv[4][4];                     // [dj][jt]

  auto loadK = [&](short8 (&fk)[4][2], int k0) {
#pragma unroll
    for (int x = 0; x < 4; x++) {
      const unsigned short* kp = kr + (size_t)(k0 + x * 16) * 64;
      fk[x][0] = *(const short8*)kp;
      fk[x][1] = *(const short8*)(kp + 32);
    }
  };
  auto loadV = [&](int k0) {
#pragma unroll
    for (int dj = 0; dj < 4; dj++)
#pragma unroll
      for (int jt = 0; jt < 4; jt++)
        cv[dj][jt] = *(const short4v*)(vr + (size_t)(dj * 16) * 2048 + k0 + jt * 16);
  };
  auto proc = [&](const short8 (&aq)[2], f32x4 (&acc)[4], float& l,
                  int q0, int k0, const short8 (&fk)[4][2]) {
    const int qabs = q0 + lid;
    f32x4 s4[4];
#pragma unroll
    for (int jt = 0; jt < 4; jt++) {
      s4[jt] = (f32x4){0.f, 0.f, 0.f, 0.f};
      s4[jt] = MFMA16(fk[jt][0], aq[0], s4[jt]);   // S^T: m=k-row, n=q
      s4[jt] = MFMA16(fk[jt][1], aq[1], s4[jt]);
    }
#pragma unroll
    for (int jt = 0; jt < 4; jt++) {
      int kbase = k0 + jt * 16 + quad * 4;
      const float* rp = relh + (qabs - kbase);
      short4v pk;
#pragma unroll
      for (int r = 0; r < 4; r++) {
        float sc = fmaf(s4[jt][r], 0.125f, rp[-r]);
        float pv = (kbase + r > qabs) ? 0.f : __expf(sc);
        l += pv;
        pk[r] = (short)f2bf(pv);
      }
#pragma unroll
      for (int dj = 0; dj < 4; dj++)
        acc[dj] = MFMAK16(cv[dj][jt], pk, acc[dj]);  // O^T += V^T x P^T
    }
  };

  int k0 = 0;
  loadK(ck, 0);
  while (true) {
    int k1 = k0 + 64;
    if (k1 < kendA) loadK(nk, k1);
    loadV(k0);
    proc(aqA, accA, lA, qA, k0, ck);
    if (k0 < kendB) proc(aqB, accB, lB, qB, k0, ck);
    if (k1 >= kendA) break;
    k0 = k1; k1 = k0 + 64;
    if (k1 < kendA) loadK(ck, k1);
    loadV(k0);
    proc(aqA, accA, lA, qA, k0, nk);
    if (k0 < kendB) proc(aqB, accB, lB, qB, k0, nk);
    if (k1 >= kendA) break;
    k0 = k1;
  }

  // epilogue: sum l across quads (q=lid fixed per lane-column), scale, store
  lA += __shfl_xor(lA, 16); lA += __shfl_xor(lA, 32);
  lB += __shfl_xor(lB, 16); lB += __shfl_xor(lB, 32);
  float rA = 1.f / lA, rB = 1.f / lB;
#pragma unroll
  for (int dj = 0; dj < 4; dj++) {
    short4v oA, oB;
#pragma unroll
    for (int r = 0; r < 4; r++) {
      oA[r] = (short)f2bf(fminf(fmaxf(accA[dj][r] * rA, -30.f), 30.f));
      oB[r] = (short)f2bf(fminf(fmaxf(accB[dj][r] * rB, -30.f), 30.f));
    }
    int d0 = dj * 16 + quad * 4;
    *(short4v*)(AOb + (size_t)(qA + lid) * 1024 + d0) = oA;
    *(short4v*)(AOb + (size_t)(qB + lid) * 1024 + d0) = oB;
  }
}

// ---------------------------------------------------------------------------
extern "C" void kernel_launch(void* const* d_in, const int* in_sizes, int n_in,
                              void* d_out, int out_size, void* d_ws, size_t ws_size,
                              hipStream_t stream) {
  const float* query  = (const float*)d_in[0];
  const float* key_in = (const float*)d_in[1];
  const float* value  = (const float*)d_in[2];
  const float* wq = (const float*)d_in[4];
  const float* bq = (const float*)d_in[5];
  const float* wk = (const float*)d_in[6];
  const float* bk = (const float*)d_in[7];
  const float* wv = (const float*)d_in[8];
  const float* bv = (const float*)d_in[9];
  const float* wo = (const float*)d_in[10];
  const float* bo = (const float*)d_in[11];
  const float* rel = (const float*)d_in[12];

  char* ws = (char*)d_ws;
  unsigned short* Xq = (unsigned short*)(ws);                 // 8.39 MB
  unsigned short* Xk = (unsigned short*)(ws + 8388608);
  unsigned short* Xv = (unsigned short*)(ws + 16777216);
  unsigned short* Wq = (unsigned short*)(ws + 25165824);      // 2.10 MB each
  unsigned short* Wk = (unsigned short*)(ws + 27262976);
  unsigned short* Wv = (unsigned short*)(ws + 29360128);
  unsigned short* Wo = (unsigned short*)(ws + 31457280);
  unsigned short* Qr  = (unsigned short*)(ws + 33554432);     // 8.39 MB
  unsigned short* Kr  = (unsigned short*)(ws + 41943040);
  unsigned short* Vtr = (unsigned short*)(ws + 50331648);     // [B,H,D,S]
  unsigned short* AOp = Xq;            // alias: Xq dead after gemm_qkv
  // tab/relt live in d_out scratch (overwritten by gemm_out at the end)
  float* out  = (float*)d_out;
  float* tab  = out;                   // 131072 floats
  float* relt = out + 131072;          // 65520 floats

  dim3 blk(256);
  prep_kernel<<<dim3(8704), blk, 0, stream>>>(
      query, key_in, value, wq, wk, wv, wo,
      Xq, Xk, Xv, Wq, Wk, Wv, Wo, tab, relt, rel);
  gemm_qkv<<<dim3(16, 32, 3), blk, 0, stream>>>(
      Xq, Xk, Xv, Wq, Wk, Wv, bq, bk, bv, Qr, Kr, Vtr);
  rope_kernel<<<dim3(256, 2), blk, 0, stream>>>(Qr, Kr, tab);
  attn_kernel<<<dim3(2048), dim3(64), 0, stream>>>(Qr, Kr, Vtr, relt, AOp);
  gemm_out<<<dim3(16, 64), blk, 0, stream>>>(AOp, Wo, bo, out);
}

// Round 8
// 398.606 us; speedup vs baseline: 1.2048x; 1.0189x over previous
//
#include <hip/hip_runtime.h>

// B=2, S=2048, HID=1024, H=16, D=64, MAX_SEQ=2048.
// Storage: fp32 holding bf16-grid values. Internal compute: bf16.

typedef __attribute__((ext_vector_type(8))) short short8;
typedef __attribute__((ext_vector_type(4))) short short4v;
typedef __attribute__((ext_vector_type(4))) float f32x4;

__device__ __forceinline__ float bf2f(unsigned short u) {
  return __uint_as_float(((unsigned int)u) << 16);
}
__device__ __forceinline__ unsigned short f2bf(float f) {
  unsigned int u = __float_as_uint(f);
  u += 0x7fffu + ((u >> 16) & 1u);   // RNE
  return (unsigned short)(u >> 16);
}

#define GLL16(gp, lp) __builtin_amdgcn_global_load_lds( \
    (const __attribute__((address_space(1))) void*)(gp), \
    (__attribute__((address_space(3))) void*)(lp), 16, 0, 0)

#define MFMA16(a, b, c)  __builtin_amdgcn_mfma_f32_16x16x32_bf16((a), (b), (c), 0, 0, 0)
#define MFMAK16(a, b, c) __builtin_amdgcn_mfma_f32_16x16x16bf16_1k((a), (b), (c), 0, 0, 0)

// ---------------------------------------------------------------------------
// prep: fp32->bf16 converts + rope cos/sin table + rel transpose.
// ---------------------------------------------------------------------------
__global__ __launch_bounds__(256) void prep_kernel(
    const float* __restrict__ q, const float* __restrict__ k,
    const float* __restrict__ v,
    const float* __restrict__ wq, const float* __restrict__ wk,
    const float* __restrict__ wv, const float* __restrict__ wo,
    unsigned short* __restrict__ xq, unsigned short* __restrict__ xk,
    unsigned short* __restrict__ xv,
    unsigned short* __restrict__ wqb, unsigned short* __restrict__ wkb,
    unsigned short* __restrict__ wvb, unsigned short* __restrict__ wob,
    float* __restrict__ tab, float* __restrict__ relt,
    const float* __restrict__ rel)
{
  int tid = blockIdx.x * 256 + threadIdx.x;
  if (tid < 2097152) {          // converts
    const float* src; unsigned short* dst; size_t off;
    if (tid < 1572864) {
      int seg = tid / 524288, rc = tid - seg * 524288;
      src = seg == 0 ? q : (seg == 1 ? k : v);
      dst = seg == 0 ? xq : (seg == 1 ? xk : xv);
      off = (size_t)rc * 8;
    } else {
      int c2 = tid - 1572864;
      int seg = c2 / 131072, rc = c2 - seg * 131072;
      src = seg == 0 ? wq : (seg == 1 ? wk : (seg == 2 ? wv : wo));
      dst = seg == 0 ? wqb : (seg == 1 ? wkb : (seg == 2 ? wvb : wob));
      off = (size_t)rc * 8;
    }
    float4 f0 = ((const float4*)(src + off))[0];
    float4 f1 = ((const float4*)(src + off))[1];
    short8 o;
    o[0]=f2bf(f0.x); o[1]=f2bf(f0.y); o[2]=f2bf(f0.z); o[3]=f2bf(f0.w);
    o[4]=f2bf(f1.x); o[5]=f2bf(f1.y); o[6]=f2bf(f1.z); o[7]=f2bf(f1.w);
    *(short8*)(dst + off) = o;
  } else if (tid < 2162688) {   // rope table
    int u = tid - 2097152;
    int s = u >> 5, j = u & 31;
    float f = expf((float)j * -0.28782313662425575f);   // 10000^(-j/32)
    float sn, cs;
    sincosf((float)s * f, &sn, &cs);
    tab[s * 64 + j] = cs;
    tab[s * 64 + 32 + j] = sn;
  } else {                      // relt[h][d] = rel[d][h]
    int u = tid - 2162688;
    int hh = u >> 12, d = u & 4095;
    if (d < 4095) relt[hh * 4095 + d] = rel[d * 16 + hh];
  }
}

// ---------------------------------------------------------------------------
// 128x64-tile GEMM core, BK=32, 4 waves (2m x 2n of 64x32), GLL16 staging.
// SWAP=true: mfma(bf,af) -> D row(quad*4+r)=n, col(lid)=m.
// ---------------------------------------------------------------------------
template<bool SWAP>
__device__ __forceinline__ void core128x64(
    const unsigned short* gA, const unsigned short* gB,
    unsigned short* As, unsigned short* Bs,
    f32x4 (&acc)[4][2], int t, int wm, int wn, int lid, int quad)
{
  for (int k0 = 0; k0 < 1024; k0 += 32) {
    __syncthreads();
    GLL16(gA + k0,         As + t * 8);
    GLL16(gA + 65536 + k0, As + 2048 + t * 8);   // rows 64..127
    GLL16(gB + k0,         Bs + t * 8);
    __syncthreads();
    short8 af[4], bf[2];
#pragma unroll
    for (int i = 0; i < 4; i++)
      af[i] = *(const short8*)(As + (wm + i * 16 + lid) * 32 + quad * 8);
#pragma unroll
    for (int j = 0; j < 2; j++)
      bf[j] = *(const short8*)(Bs + (wn + j * 16 + lid) * 32 + quad * 8);
#pragma unroll
    for (int i = 0; i < 4; i++)
#pragma unroll
      for (int j = 0; j < 2; j++)
        acc[i][j] = SWAP ? MFMA16(bf[j], af[i], acc[i][j])
                         : MFMA16(af[i], bf[j], acc[i][j]);
  }
}

// QKV projections: z=0 Q, z=1 K (scatter [B,H,S,D]); z=2 V (scatter [B,H,D,S]).
__global__ __launch_bounds__(256) void gemm_qkv(
    const unsigned short* __restrict__ Xq, const unsigned short* __restrict__ Xk,
    const unsigned short* __restrict__ Xv,
    const unsigned short* __restrict__ Wq, const unsigned short* __restrict__ Wk,
    const unsigned short* __restrict__ Wv,
    const float* __restrict__ bq, const float* __restrict__ bk,
    const float* __restrict__ bv,
    unsigned short* __restrict__ Qr, unsigned short* __restrict__ Kr,
    unsigned short* __restrict__ Vtr)
{
  __shared__ unsigned short As[128 * 32];
  __shared__ unsigned short Bs[64 * 32];
  const int z = blockIdx.z;
  const unsigned short* X = z == 0 ? Xq : (z == 1 ? Xk : Xv);
  const unsigned short* W = z == 0 ? Wq : (z == 1 ? Wk : Wv);
  const float* Bi = z == 0 ? bq : (z == 1 ? bk : bv);
  unsigned short* O = z == 0 ? Qr : (z == 1 ? Kr : Vtr);

  const int t    = threadIdx.x;
  const int lane = t & 63;
  const int lid  = lane & 15;
  const int quad = lane >> 4;
  const int w    = t >> 6;
  const int wm   = (w >> 1) * 64;
  const int wn   = (w & 1) * 32;
  const int m0   = blockIdx.y * 128;
  const int n0   = blockIdx.x * 64;

  const unsigned short* gA = X + (size_t)(m0 + (t >> 2)) * 1024 + (t & 3) * 8;
  const unsigned short* gB = W + (size_t)(n0 + (t >> 2)) * 1024 + (t & 3) * 8;

  f32x4 acc[4][2];
#pragma unroll
  for (int i = 0; i < 4; i++)
#pragma unroll
    for (int j = 0; j < 2; j++) acc[i][j] = (f32x4){0.f, 0.f, 0.f, 0.f};

  if (z == 2) core128x64<false>(gA, gB, As, Bs, acc, t, wm, wn, lid, quad);
  else        core128x64<true >(gA, gB, As, Bs, acc, t, wm, wn, lid, quad);

  if (z < 2) {   // swapped: row->n(d), col->m(s); short4 along d
#pragma unroll
    for (int jn = 0; jn < 2; jn++) {
      int nn = n0 + wn + jn * 16 + quad * 4;
      int hh = nn >> 6, d0 = nn & 63;
      float4 b4 = *(const float4*)(Bi + nn);
#pragma unroll
      for (int im = 0; im < 4; im++) {
        int m = m0 + wm + im * 16 + lid;
        int bb = m >> 11, s = m & 2047;
        short4v pk;
        pk[0] = (short)f2bf(acc[im][jn][0] + b4.x);
        pk[1] = (short)f2bf(acc[im][jn][1] + b4.y);
        pk[2] = (short)f2bf(acc[im][jn][2] + b4.z);
        pk[3] = (short)f2bf(acc[im][jn][3] + b4.w);
        *(short4v*)(O + ((size_t)((bb * 16 + hh) * 2048 + s)) * 64 + d0) = pk;
      }
    }
  } else {       // unswapped: row->m(s), col->n(d); short4 along s into [B,H,D,S]
#pragma unroll
    for (int j = 0; j < 2; j++) {
      int n = n0 + wn + j * 16 + lid;
      int hh = n >> 6, d = n & 63;
      float bvv = Bi[n];
#pragma unroll
      for (int i = 0; i < 4; i++) {
        int mr = m0 + wm + i * 16 + quad * 4;
        int bb = mr >> 11, s0 = mr & 2047;
        short4v pk;
        pk[0] = (short)f2bf(acc[i][j][0] + bvv);
        pk[1] = (short)f2bf(acc[i][j][1] + bvv);
        pk[2] = (short)f2bf(acc[i][j][2] + bvv);
        pk[3] = (short)f2bf(acc[i][j][3] + bvv);
        *(short4v*)(O + ((size_t)((bb * 16 + hh) * 64 + d)) * 2048 + s0) = pk;
      }
    }
  }
}

// ---------------------------------------------------------------------------
// Output projection: 64x64 tiles, 1024 blocks. fp32 float4 output.
// ---------------------------------------------------------------------------
__global__ __launch_bounds__(256) void gemm_out(
    const unsigned short* __restrict__ X, const unsigned short* __restrict__ W,
    const float* __restrict__ Bi, float* __restrict__ O)
{
  __shared__ unsigned short As[64 * 32];
  __shared__ unsigned short Bs[64 * 32];
  const int t    = threadIdx.x;
  const int lane = t & 63;
  const int lid  = lane & 15;
  const int quad = lane >> 4;
  const int w    = t >> 6;
  const int wm   = (w >> 1) * 32;
  const int wn   = (w & 1) * 32;
  const int m0   = blockIdx.y * 64;
  const int n0   = blockIdx.x * 64;

  const unsigned short* gA = X + (size_t)(m0 + (t >> 2)) * 1024 + (t & 3) * 8;
  const unsigned short* gB = W + (size_t)(n0 + (t >> 2)) * 1024 + (t & 3) * 8;

  f32x4 acc[2][2];
#pragma unroll
  for (int i = 0; i < 2; i++)
#pragma unroll
    for (int j = 0; j < 2; j++) acc[i][j] = (f32x4){0.f, 0.f, 0.f, 0.f};

  for (int k0 = 0; k0 < 1024; k0 += 32) {
    __syncthreads();
    GLL16(gA + k0, As + t * 8);
    GLL16(gB + k0, Bs + t * 8);
    __syncthreads();
    short8 af[2], bf[2];
#pragma unroll
    for (int i = 0; i < 2; i++)
      af[i] = *(const short8*)(As + (wm + i * 16 + lid) * 32 + quad * 8);
#pragma unroll
    for (int j = 0; j < 2; j++)
      bf[j] = *(const short8*)(Bs + (wn + j * 16 + lid) * 32 + quad * 8);
#pragma unroll
    for (int i = 0; i < 2; i++)
#pragma unroll
      for (int j = 0; j < 2; j++)
        acc[i][j] = MFMA16(bf[j], af[i], acc[i][j]);   // swapped
  }
#pragma unroll
  for (int jn = 0; jn < 2; jn++) {
    int nn = n0 + wn + jn * 16 + quad * 4;
    float4 b4 = *(const float4*)(Bi + nn);
#pragma unroll
    for (int im = 0; im < 2; im++) {
      int m = m0 + wm + im * 16 + lid;
      float4 ov;
      ov.x = acc[im][jn][0] + b4.x;
      ov.y = acc[im][jn][1] + b4.y;
      ov.z = acc[im][jn][2] + b4.z;
      ov.w = acc[im][jn][3] + b4.w;
      *(float4*)(O + (size_t)m * 1024 + nn) = ov;
    }
  }
}

// ---------------------------------------------------------------------------
// RoPE apply (reference variant), in-place on bf16 [B,H,S,64].
// ---------------------------------------------------------------------------
__global__ __launch_bounds__(256) void rope_kernel(unsigned short* __restrict__ Q,
                                                   unsigned short* __restrict__ Kp,
                                                   const float* __restrict__ tab)
{
  int row = blockIdx.x * 256 + threadIdx.x;
  unsigned short* P = ((blockIdx.y == 0) ? Q : Kp) + (size_t)row * 64;
  const float* tr = tab + (size_t)(row & 2047) * 64;

  short8 xv[8];
#pragma unroll
  for (int c = 0; c < 8; c++) xv[c] = *(const short8*)(P + c * 8);
#define XE(i) bf2f((unsigned short)xv[(i) >> 3][(i) & 7])
  short8 ov[8];
#pragma unroll
  for (int j = 0; j < 32; j++) {
    float cs = tr[j], sn = tr[32 + j];
    float yl = XE(j) * cs      - XE(2 * j + 1) * sn;
    float yh = XE(j + 32) * cs + XE(2 * j)     * sn;
    ov[j >> 3][j & 7]       = (short)f2bf(yl);
    ov[(j >> 3) + 4][j & 7] = (short)f2bf(yh);
  }
#undef XE
#pragma unroll
  for (int c = 0; c < 8; c++) *(short8*)(P + c * 8) = ov[c];
}

// ---------------------------------------------------------------------------
// Flash attention: LDS-free k-loop (r7 math) + IN-BLOCK split-K (r8).
// Block = 4 waves on one (bh, strip-pair); wave w takes k-iters w, w+4, ...
// (disjoint segments -> no K/V read duplication, partials stay in LDS).
// S^T = mfma(K,Q) C-layout == B-operand of 16x16x16bf16 -> PV direct from
// regs; O^T accum; per-wave l per-lane. End: dump partials to padded LDS,
// one __syncthreads, cooperative combine -> bf16 AO.
// ---------------------------------------------------------------------------
__global__ __launch_bounds__(256) void attn_kernel(
    const unsigned short* __restrict__ Q, const unsigned short* __restrict__ Kg,
    const unsigned short* __restrict__ Vt, const float* __restrict__ relt,
    unsigned short* __restrict__ AO)
{
  __shared__ float Osum[8][1088];     // [wave*2+strip][d*17 + q]  (pad 17)
  __shared__ float Lsum[8][16];

  const int t    = threadIdx.x;
  const int lane = t & 63;
  const int lid  = lane & 15;
  const int quad = lane >> 4;
  const int w    = t >> 6;
  const int jid  = blockIdx.x;          // 0..2047, bh-major
  const int bh   = jid >> 6;
  const int p    = jid & 63;
  const int h    = bh & 15;
  const int qA   = 2032 - 16 * p;       // heavy strip rows [qA, qA+16)
  const int qB   = 16 * p;              // light strip rows [qB, qB+16)
  const int nA   = (qA + 79) >> 6;      // k-iters for A (covers B's too)
  const int nB   = (qB + 79) >> 6;

  const unsigned short* Qb = Q  + (size_t)bh * (2048 * 64);
  const unsigned short* Kb = Kg + (size_t)bh * (2048 * 64);
  const unsigned short* Vb = Vt + (size_t)bh * (64 * 2048);
  const float* relh = relt + h * 4095 + 2047;
  unsigned short* AOb = AO + (size_t)(bh >> 4) * (2048 * 1024) + h * 64;

  // Q as B-operand frags (n=lid -> q, k=quad*8+j -> d)
  short8 aqA[2], aqB[2];
  {
    const unsigned short* qp = Qb + (size_t)(qA + lid) * 64;
    aqA[0] = *(const short8*)(qp + quad * 8);
    aqA[1] = *(const short8*)(qp + 32 + quad * 8);
    qp = Qb + (size_t)(qB + lid) * 64;
    aqB[0] = *(const short8*)(qp + quad * 8);
    aqB[1] = *(const short8*)(qp + 32 + quad * 8);
  }

  f32x4 accA[4], accB[4];               // O^T C-layout per 16-d block
  float lA = 0.f, lB = 0.f;             // per-lane partial denominators
#pragma unroll
  for (int dj = 0; dj < 4; dj++) {
    accA[dj] = (f32x4){0.f, 0.f, 0.f, 0.f};
    accB[dj] = (f32x4){0.f, 0.f, 0.f, 0.f};
  }

  const unsigned short* kr = Kb + (size_t)lid * 64 + quad * 8;
  const unsigned short* vr = Vb + (size_t)lid * 2048 + quad * 4;   // V^T A-frag base

  short8 ck[4][2];
  short4v cv[4][4];                     // [dj][jt]

  auto loadK = [&](int k0) {
#pragma unroll
    for (int x = 0; x < 4; x++) {
      const unsigned short* kp = kr + (size_t)(k0 + x * 16) * 64;
      ck[x][0] = *(const short8*)kp;
      ck[x][1] = *(const short8*)(kp + 32);
    }
  };
  auto loadV = [&](int k0) {
#pragma unroll
    for (int dj = 0; dj < 4; dj++)
#pragma unroll
      for (int jt = 0; jt < 4; jt++)
        cv[dj][jt] = *(const short4v*)(vr + (size_t)(dj * 16) * 2048 + k0 + jt * 16);
  };
  auto proc = [&](const short8 (&aq)[2], f32x4 (&acc)[4], float& l,
                  int q0, int k0) {
    const int qabs = q0 + lid;
    f32x4 s4[4];
#pragma unroll
    for (int jt = 0; jt < 4; jt++) {
      s4[jt] = (f32x4){0.f, 0.f, 0.f, 0.f};
      s4[jt] = MFMA16(ck[jt][0], aq[0], s4[jt]);   // S^T: m=k-row, n=q
      s4[jt] = MFMA16(ck[jt][1], aq[1], s4[jt]);
    }
#pragma unroll
    for (int jt = 0; jt < 4; jt++) {
      int kbase = k0 + jt * 16 + quad * 4;
      const float* rp = relh + (qabs - kbase);
      short4v pk;
#pragma unroll
      for (int r = 0; r < 4; r++) {
        float sc = fmaf(s4[jt][r], 0.125f, rp[-r]);
        float pv = (kbase + r > qabs) ? 0.f : __expf(sc);
        l += pv;
        pk[r] = (short)f2bf(pv);
      }
#pragma unroll
      for (int dj = 0; dj < 4; dj++)
        acc[dj] = MFMAK16(cv[dj][jt], pk, acc[dj]);  // O^T += V^T x P^T
    }
  };

  for (int it = w; it < nA; it += 4) {
    int k0 = it * 64;
    loadK(k0);
    loadV(k0);
    proc(aqA, accA, lA, qA, k0);
    if (it < nB) proc(aqB, accB, lB, qB, k0);
  }

  // per-wave: finish l (sum over quads; q=lid per lane-column), dump partials
  lA += __shfl_xor(lA, 16); lA += __shfl_xor(lA, 32);
  lB += __shfl_xor(lB, 16); lB += __shfl_xor(lB, 32);
#pragma unroll
  for (int dj = 0; dj < 4; dj++)
#pragma unroll
    for (int r = 0; r < 4; r++) {
      int d = dj * 16 + quad * 4 + r;
      Osum[w * 2 + 0][d * 17 + lid] = accA[dj][r];
      Osum[w * 2 + 1][d * 17 + lid] = accB[dj][r];
    }
  if (quad == 0) {
    Lsum[w * 2 + 0][lid] = lA;
    Lsum[w * 2 + 1][lid] = lB;
  }
  __syncthreads();

  // cooperative combine: thread -> (q = t>>4, d0 = (t&15)*4), both strips
  const int cq = t >> 4;
  const int d0 = (t & 15) * 4;
#pragma unroll
  for (int s = 0; s < 2; s++) {
    float a0 = 0.f, a1 = 0.f, a2 = 0.f, a3 = 0.f, l = 0.f;
#pragma unroll
    for (int w2 = 0; w2 < 4; w2++) {
      const float* src = &Osum[w2 * 2 + s][0];
      a0 += src[(d0 + 0) * 17 + cq];
      a1 += src[(d0 + 1) * 17 + cq];
      a2 += src[(d0 + 2) * 17 + cq];
      a3 += src[(d0 + 3) * 17 + cq];
      l  += Lsum[w2 * 2 + s][cq];
    }
    float rcp = 1.f / l;
    short4v pk;
    pk[0] = (short)f2bf(fminf(fmaxf(a0 * rcp, -30.f), 30.f));
    pk[1] = (short)f2bf(fminf(fmaxf(a1 * rcp, -30.f), 30.f));
    pk[2] = (short)f2bf(fminf(fmaxf(a2 * rcp, -30.f), 30.f));
    pk[3] = (short)f2bf(fminf(fmaxf(a3 * rcp, -30.f), 30.f));
    int qrow = (s == 0 ? qA : qB) + cq;
    *(short4v*)(AOb + (size_t)qrow * 1024 + d0) = pk;
  }
}

// ---------------------------------------------------------------------------
extern "C" void kernel_launch(void* const* d_in, const int* in_sizes, int n_in,
                              void* d_out, int out_size, void* d_ws, size_t ws_size,
                              hipStream_t stream) {
  const float* query  = (const float*)d_in[0];
  const float* key_in = (const float*)d_in[1];
  const float* value  = (const float*)d_in[2];
  const float* wq = (const float*)d_in[4];
  const float* bq = (const float*)d_in[5];
  const float* wk = (const float*)d_in[6];
  const float* bk = (const float*)d_in[7];
  const float* wv = (const float*)d_in[8];
  const float* bv = (const float*)d_in[9];
  const float* wo = (const float*)d_in[10];
  const float* bo = (const float*)d_in[11];
  const float* rel = (const float*)d_in[12];

  char* ws = (char*)d_ws;
  unsigned short* Xq = (unsigned short*)(ws);                 // 8.39 MB
  unsigned short* Xk = (unsigned short*)(ws + 8388608);
  unsigned short* Xv = (unsigned short*)(ws + 16777216);
  unsigned short* Wq = (unsigned short*)(ws + 25165824);      // 2.10 MB each
  unsigned short* Wk = (unsigned short*)(ws + 27262976);
  unsigned short* Wv = (unsigned short*)(ws + 29360128);
  unsigned short* Wo = (unsigned short*)(ws + 31457280);
  unsigned short* Qr  = (unsigned short*)(ws + 33554432);     // 8.39 MB
  unsigned short* Kr  = (unsigned short*)(ws + 41943040);
  unsigned short* Vtr = (unsigned short*)(ws + 50331648);     // [B,H,D,S]
  unsigned short* AOp = Xq;            // alias: Xq dead after gemm_qkv
  // tab/relt live in d_out scratch (overwritten by gemm_out at the end)
  float* out  = (float*)d_out;
  float* tab  = out;                   // 131072 floats
  float* relt = out + 131072;          // 65520 floats

  dim3 blk(256);
  prep_kernel<<<dim3(8704), blk, 0, stream>>>(
      query, key_in, value, wq, wk, wv, wo,
      Xq, Xk, Xv, Wq, Wk, Wv, Wo, tab, relt, rel);
  gemm_qkv<<<dim3(16, 32, 3), blk, 0, stream>>>(
      Xq, Xk, Xv, Wq, Wk, Wv, bq, bk, bv, Qr, Kr, Vtr);
  rope_kernel<<<dim3(256, 2), blk, 0, stream>>>(Qr, Kr, tab);
  attn_kernel<<<dim3(2048), blk, 0, stream>>>(Qr, Kr, Vtr, relt, AOp);
  gemm_out<<<dim3(16, 64), blk, 0, stream>>>(AOp, Wo, bo, out);
}

// Round 9
// 351.305 us; speedup vs baseline: 1.3670x; 1.1346x over previous
//
#include <hip/hip_runtime.h>

// B=2, S=2048, HID=1024, H=16, D=64, MAX_SEQ=2048.
// Storage: fp32 holding bf16-grid values. Internal compute: bf16.

typedef __attribute__((ext_vector_type(8))) short short8;
typedef __attribute__((ext_vector_type(4))) short short4v;
typedef __attribute__((ext_vector_type(4))) float f32x4;

__device__ __forceinline__ float bf2f(unsigned short u) {
  return __uint_as_float(((unsigned int)u) << 16);
}
__device__ __forceinline__ unsigned short f2bf(float f) {
  unsigned int u = __float_as_uint(f);
  u += 0x7fffu + ((u >> 16) & 1u);   // RNE
  return (unsigned short)(u >> 16);
}

#define GLL16(gp, lp) __builtin_amdgcn_global_load_lds( \
    (const __attribute__((address_space(1))) void*)(gp), \
    (__attribute__((address_space(3))) void*)(lp), 16, 0, 0)

#define MFMA16(a, b, c)  __builtin_amdgcn_mfma_f32_16x16x32_bf16((a), (b), (c), 0, 0, 0)

// ---------------------------------------------------------------------------
// prep: fp32->bf16 converts + rope cos/sin table + rel transpose.
// ---------------------------------------------------------------------------
__global__ __launch_bounds__(256) void prep_kernel(
    const float* __restrict__ q, const float* __restrict__ k,
    const float* __restrict__ v,
    const float* __restrict__ wq, const float* __restrict__ wk,
    const float* __restrict__ wv, const float* __restrict__ wo,
    unsigned short* __restrict__ xq, unsigned short* __restrict__ xk,
    unsigned short* __restrict__ xv,
    unsigned short* __restrict__ wqb, unsigned short* __restrict__ wkb,
    unsigned short* __restrict__ wvb, unsigned short* __restrict__ wob,
    float* __restrict__ tab, float* __restrict__ relt,
    const float* __restrict__ rel)
{
  int tid = blockIdx.x * 256 + threadIdx.x;
  if (tid < 2097152) {          // converts
    const float* src; unsigned short* dst; size_t off;
    if (tid < 1572864) {
      int seg = tid / 524288, rc = tid - seg * 524288;
      src = seg == 0 ? q : (seg == 1 ? k : v);
      dst = seg == 0 ? xq : (seg == 1 ? xk : xv);
      off = (size_t)rc * 8;
    } else {
      int c2 = tid - 1572864;
      int seg = c2 / 131072, rc = c2 - seg * 131072;
      src = seg == 0 ? wq : (seg == 1 ? wk : (seg == 2 ? wv : wo));
      dst = seg == 0 ? wqb : (seg == 1 ? wkb : (seg == 2 ? wvb : wob));
      off = (size_t)rc * 8;
    }
    float4 f0 = ((const float4*)(src + off))[0];
    float4 f1 = ((const float4*)(src + off))[1];
    short8 o;
    o[0]=f2bf(f0.x); o[1]=f2bf(f0.y); o[2]=f2bf(f0.z); o[3]=f2bf(f0.w);
    o[4]=f2bf(f1.x); o[5]=f2bf(f1.y); o[6]=f2bf(f1.z); o[7]=f2bf(f1.w);
    *(short8*)(dst + off) = o;
  } else if (tid < 2162688) {   // rope table
    int u = tid - 2097152;
    int s = u >> 5, j = u & 31;
    float f = expf((float)j * -0.28782313662425575f);   // 10000^(-j/32)
    float sn, cs;
    sincosf((float)s * f, &sn, &cs);
    tab[s * 64 + j] = cs;
    tab[s * 64 + 32 + j] = sn;
  } else {                      // relt[h][d] = rel[d][h]
    int u = tid - 2162688;
    int hh = u >> 12, d = u & 4095;
    if (d < 4095) relt[hh * 4095 + d] = rel[d * 16 + hh];
  }
}

// ---------------------------------------------------------------------------
// Fused QKV GEMM, m97 structure: 128x128 tile, BK=32, 16 MFMA/iter, GLL16.
// N=3072 (Wcat = Wq|Wk|Wv contiguous); z = n0>>10 selects X/bias/output.
// z<2 (Q,K): swapped mfma -> r along n(=d) -> short4 scatter [B,H,S,D].
// z==2 (V): unswapped -> r along m(=s) -> short4 scatter [B,H,D,S].
// Grid 24 x 32 = 768 blocks.
// ---------------------------------------------------------------------------
template<bool SWAP>
__device__ __forceinline__ void core128x128(
    const unsigned short* gA, const unsigned short* gB,
    unsigned short* As, unsigned short* Bs,
    f32x4 (&acc)[4][4], int t, int wm, int wn, int lid, int quad)
{
  for (int k0 = 0; k0 < 1024; k0 += 32) {
    __syncthreads();
    GLL16(gA + k0,         As + t * 8);
    GLL16(gA + 65536 + k0, As + 2048 + t * 8);   // rows 64..127
    GLL16(gB + k0,         Bs + t * 8);
    GLL16(gB + 65536 + k0, Bs + 2048 + t * 8);
    __syncthreads();
    short8 af[4], bf[4];
#pragma unroll
    for (int i = 0; i < 4; i++)
      af[i] = *(const short8*)(As + (wm + i * 16 + lid) * 32 + quad * 8);
#pragma unroll
    for (int j = 0; j < 4; j++)
      bf[j] = *(const short8*)(Bs + (wn + j * 16 + lid) * 32 + quad * 8);
#pragma unroll
    for (int i = 0; i < 4; i++)
#pragma unroll
      for (int j = 0; j < 4; j++)
        acc[i][j] = SWAP ? MFMA16(bf[j], af[i], acc[i][j])
                         : MFMA16(af[i], bf[j], acc[i][j]);
  }
}

__global__ __launch_bounds__(256) void gemm_qkv(
    const unsigned short* __restrict__ Xq, const unsigned short* __restrict__ Xk,
    const unsigned short* __restrict__ Xv,
    const unsigned short* __restrict__ Wcat,
    const float* __restrict__ bq, const float* __restrict__ bk,
    const float* __restrict__ bv,
    unsigned short* __restrict__ Qr, unsigned short* __restrict__ Kr,
    unsigned short* __restrict__ Vtr)
{
  __shared__ unsigned short As[128 * 32];
  __shared__ unsigned short Bs[128 * 32];

  const int t    = threadIdx.x;
  const int lane = t & 63;
  const int lid  = lane & 15;
  const int quad = lane >> 4;
  const int w    = t >> 6;
  const int wm   = (w >> 1) * 64;
  const int wn   = (w & 1) * 64;
  const int n0   = blockIdx.x * 128;
  const int m0   = blockIdx.y * 128;
  const int z    = n0 >> 10;                      // 0=Q 1=K 2=V

  const unsigned short* X = z == 0 ? Xq : (z == 1 ? Xk : Xv);
  const float* Bi = z == 0 ? bq : (z == 1 ? bk : bv);

  const unsigned short* gA = X    + (size_t)(m0 + (t >> 2)) * 1024 + (t & 3) * 8;
  const unsigned short* gB = Wcat + (size_t)(n0 + (t >> 2)) * 1024 + (t & 3) * 8;

  f32x4 acc[4][4];
#pragma unroll
  for (int i = 0; i < 4; i++)
#pragma unroll
    for (int j = 0; j < 4; j++) acc[i][j] = (f32x4){0.f, 0.f, 0.f, 0.f};

  if (z == 2) core128x128<false>(gA, gB, As, Bs, acc, t, wm, wn, lid, quad);
  else        core128x128<true >(gA, gB, As, Bs, acc, t, wm, wn, lid, quad);

  if (z < 2) {   // swapped: D row(quad*4+r)=n(d), col(lid)=m(s); short4 along d
    unsigned short* O = z == 0 ? Qr : Kr;
#pragma unroll
    for (int jn = 0; jn < 4; jn++) {
      int nn = n0 + wn + jn * 16 + quad * 4;      // absolute col in [z*1024 ..)
      int nc = nn & 1023;
      int hh = nc >> 6, d0 = nc & 63;
      float4 b4 = *(const float4*)(Bi + nc);
#pragma unroll
      for (int im = 0; im < 4; im++) {
        int m = m0 + wm + im * 16 + lid;
        int bb = m >> 11, s = m & 2047;
        short4v pk;
        pk[0] = (short)f2bf(acc[im][jn][0] + b4.x);
        pk[1] = (short)f2bf(acc[im][jn][1] + b4.y);
        pk[2] = (short)f2bf(acc[im][jn][2] + b4.z);
        pk[3] = (short)f2bf(acc[im][jn][3] + b4.w);
        *(short4v*)(O + ((size_t)((bb * 16 + hh) * 2048 + s)) * 64 + d0) = pk;
      }
    }
  } else {       // unswapped: row=m(s), col=n(d); short4 along s into [B,H,D,S]
#pragma unroll
    for (int j = 0; j < 4; j++) {
      int n = n0 + wn + j * 16 + lid;
      int nc = n & 1023;
      int hh = nc >> 6, d = nc & 63;
      float bvv = Bi[nc];
#pragma unroll
      for (int i = 0; i < 4; i++) {
        int mr = m0 + wm + i * 16 + quad * 4;
        int bb = mr >> 11, s0 = mr & 2047;
        short4v pk;
        pk[0] = (short)f2bf(acc[i][j][0] + bvv);
        pk[1] = (short)f2bf(acc[i][j][1] + bvv);
        pk[2] = (short)f2bf(acc[i][j][2] + bvv);
        pk[3] = (short)f2bf(acc[i][j][3] + bvv);
        *(short4v*)(Vtr + ((size_t)((bb * 16 + hh) * 64 + d)) * 2048 + s0) = pk;
      }
    }
  }
}

// ---------------------------------------------------------------------------
// Output projection: 128x64 tile, BK=64 (16 MFMA + 6 GLL16 per barrier-pair),
// 24 KB LDS, grid 16 x 32 = 512 blocks. fp32 float4 output.
// ---------------------------------------------------------------------------
__global__ __launch_bounds__(256) void gemm_out(
    const unsigned short* __restrict__ X, const unsigned short* __restrict__ W,
    const float* __restrict__ Bi, float* __restrict__ O)
{
  __shared__ unsigned short As[128 * 64];   // 16 KB
  __shared__ unsigned short Bs[64 * 64];    // 8 KB
  const int t    = threadIdx.x;
  const int lane = t & 63;
  const int lid  = lane & 15;
  const int quad = lane >> 4;
  const int w    = t >> 6;
  const int wm   = (w >> 1) * 64;
  const int wn   = (w & 1) * 32;
  const int m0   = blockIdx.y * 128;
  const int n0   = blockIdx.x * 64;

  // chunk c (16B): row = c>>3, kk = (c&7)*8
  const unsigned short* gA = X + (size_t)(m0 + (t >> 3)) * 1024 + (t & 7) * 8;
  const unsigned short* gB = W + (size_t)(n0 + (t >> 3)) * 1024 + (t & 7) * 8;

  f32x4 acc[4][2];
#pragma unroll
  for (int i = 0; i < 4; i++)
#pragma unroll
    for (int j = 0; j < 2; j++) acc[i][j] = (f32x4){0.f, 0.f, 0.f, 0.f};

  for (int k0 = 0; k0 < 1024; k0 += 64) {
    __syncthreads();
#pragma unroll
    for (int i = 0; i < 4; i++)                     // A: 128 rows x 64 k
      GLL16(gA + (size_t)(i * 32) * 1024 + k0, As + (i * 256 + t) * 8);
#pragma unroll
    for (int i = 0; i < 2; i++)                     // B: 64 rows x 64 k
      GLL16(gB + (size_t)(i * 32) * 1024 + k0, Bs + (i * 256 + t) * 8);
    __syncthreads();
#pragma unroll
    for (int ks = 0; ks < 2; ks++) {
      short8 af[4], bf[2];
#pragma unroll
      for (int i = 0; i < 4; i++)
        af[i] = *(const short8*)(As + (wm + i * 16 + lid) * 64 + ks * 32 + quad * 8);
#pragma unroll
      for (int j = 0; j < 2; j++)
        bf[j] = *(const short8*)(Bs + (wn + j * 16 + lid) * 64 + ks * 32 + quad * 8);
#pragma unroll
      for (int i = 0; i < 4; i++)
#pragma unroll
        for (int j = 0; j < 2; j++)
          acc[i][j] = MFMA16(bf[j], af[i], acc[i][j]);   // swapped
    }
  }
#pragma unroll
  for (int jn = 0; jn < 2; jn++) {
    int nn = n0 + wn + jn * 16 + quad * 4;
    float4 b4 = *(const float4*)(Bi + nn);
#pragma unroll
    for (int im = 0; im < 4; im++) {
      int m = m0 + wm + im * 16 + lid;
      float4 ov;
      ov.x = acc[im][jn][0] + b4.x;
      ov.y = acc[im][jn][1] + b4.y;
      ov.z = acc[im][jn][2] + b4.z;
      ov.w = acc[im][jn][3] + b4.w;
      *(float4*)(O + (size_t)m * 1024 + nn) = ov;
    }
  }
}

// ---------------------------------------------------------------------------
// RoPE apply (reference variant), in-place on bf16 [B,H,S,64].
// ---------------------------------------------------------------------------
__global__ __launch_bounds__(256) void rope_kernel(unsigned short* __restrict__ Q,
                                                   unsigned short* __restrict__ Kp,
                                                   const float* __restrict__ tab)
{
  int row = blockIdx.x * 256 + threadIdx.x;
  unsigned short* P = ((blockIdx.y == 0) ? Q : Kp) + (size_t)row * 64;
  const float* tr = tab + (size_t)(row & 2047) * 64;

  short8 xv[8];
#pragma unroll
  for (int c = 0; c < 8; c++) xv[c] = *(const short8*)(P + c * 8);
#define XE(i) bf2f((unsigned short)xv[(i) >> 3][(i) & 7])
  short8 ov[8];
#pragma unroll
  for (int j = 0; j < 32; j++) {
    float cs = tr[j], sn = tr[32 + j];
    float yl = XE(j) * cs      - XE(2 * j + 1) * sn;
    float yh = XE(j + 32) * cs + XE(2 * j)     * sn;
    ov[j >> 3][j & 7]       = (short)f2bf(yl);
    ov[(j >> 3) + 4][j & 7] = (short)f2bf(yh);
  }
#undef XE
#pragma unroll
  for (int c = 0; c < 8; c++) *(short8*)(P + c * 8) = ov[c];
}

// ---------------------------------------------------------------------------
// Flash attention (round-5 best: 134 us): exp-direct softmax, paired 16-row
// strips (uniform work), wave-autonomous, K prefetch, LDS P round-trip.
// 2048 blocks x 1 wave.
// ---------------------------------------------------------------------------
__global__ __launch_bounds__(64, 2) void attn_kernel(
    const unsigned short* __restrict__ Q, const unsigned short* __restrict__ Kg,
    const unsigned short* __restrict__ Vt, const float* __restrict__ relt,
    unsigned short* __restrict__ AO)
{
  __shared__ unsigned short Ps[32 * 72];

  const int lane = threadIdx.x;
  const int lid  = lane & 15;
  const int quad = lane >> 4;
  const int jid  = blockIdx.x;          // 0..2047
  const int bh   = jid >> 6;
  const int p    = jid & 63;
  const int h    = bh & 15;
  const int qA   = 2032 - 16 * p;       // heavy strip rows [qA, qA+16)
  const int qB   = 16 * p;              // light strip rows [qB, qB+16)
  const int kendA = qA + 16, kendB = qB + 16;

  const unsigned short* Qb = Q  + (size_t)bh * (2048 * 64);
  const unsigned short* Kb = Kg + (size_t)bh * (2048 * 64);
  const unsigned short* Vb = Vt + (size_t)bh * (64 * 2048);
  const float* relh = relt + h * 4095 + 2047;
  unsigned short* AOb = AO + (size_t)(bh >> 4) * (2048 * 1024) + h * 64;

  short8 aqA[2], aqB[2];
  {
    const unsigned short* qp = Qb + (size_t)(qA + lid) * 64;
    aqA[0] = *(const short8*)(qp + quad * 8);
    aqA[1] = *(const short8*)(qp + 32 + quad * 8);
    qp = Qb + (size_t)(qB + lid) * 64;
    aqB[0] = *(const short8*)(qp + quad * 8);
    aqB[1] = *(const short8*)(qp + 32 + quad * 8);
  }

  f32x4 accA[4], accB[4];
  float lA[4] = {0.f, 0.f, 0.f, 0.f}, lB[4] = {0.f, 0.f, 0.f, 0.f};
#pragma unroll
  for (int dj = 0; dj < 4; dj++) {
    accA[dj] = (f32x4){0.f, 0.f, 0.f, 0.f};
    accB[dj] = (f32x4){0.f, 0.f, 0.f, 0.f};
  }

  const unsigned short* kr = Kb + (size_t)lid * 64 + quad * 8;
  const unsigned short* vr = Vb + (size_t)lid * 2048 + quad * 8;

  short8 ck[4][2], nk[4][2], cv[4][2];

  auto loadK = [&](short8 (&fk)[4][2], int k0) {
#pragma unroll
    for (int x = 0; x < 4; x++) {
      const unsigned short* kp = kr + (size_t)(k0 + x * 16) * 64;
      fk[x][0] = *(const short8*)kp;
      fk[x][1] = *(const short8*)(kp + 32);
    }
  };
  auto loadV = [&](short8 (&fv)[4][2], int k0) {
#pragma unroll
    for (int x = 0; x < 4; x++) {
      const unsigned short* vp = vr + (size_t)(x * 16) * 2048 + k0;
      fv[x][0] = *(const short8*)vp;
      fv[x][1] = *(const short8*)(vp + 32);
    }
  };
  auto proc = [&](const short8 (&aq)[2], f32x4 (&acc)[4], float (&l)[4],
                  int qr0, int k0, const short8 (&fk)[4][2],
                  const short8 (&fv)[4][2], int pbase) {
    f32x4 s4[4];
#pragma unroll
    for (int jt = 0; jt < 4; jt++) {
      s4[jt] = (f32x4){0.f, 0.f, 0.f, 0.f};
      s4[jt] = MFMA16(aq[0], fk[jt][0], s4[jt]);
      s4[jt] = MFMA16(aq[1], fk[jt][1], s4[jt]);
    }
#pragma unroll
    for (int jt = 0; jt < 4; jt++) {
      int kb = k0 + jt * 16 + lid;
      const float* rp = relh + (qr0 - kb);
#pragma unroll
      for (int r = 0; r < 4; r++) {
        float sc = fmaf(s4[jt][r], 0.125f, rp[r]);
        float pv = (kb > qr0 + r) ? 0.f : __expf(sc);
        l[r] += pv;
        Ps[(pbase + quad * 4 + r) * 72 + jt * 16 + lid] = f2bf(pv);
      }
    }
    short8 ap0 = *(const short8*)(Ps + (pbase + lid) * 72 + quad * 8);
    short8 ap1 = *(const short8*)(Ps + (pbase + lid) * 72 + 32 + quad * 8);
#pragma unroll
    for (int dj = 0; dj < 4; dj++) {
      acc[dj] = MFMA16(ap0, fv[dj][0], acc[dj]);
      acc[dj] = MFMA16(ap1, fv[dj][1], acc[dj]);
    }
  };

  const int qrA = qA + quad * 4, qrB = qB + quad * 4;
  int k0 = 0;
  loadK(ck, 0);
  while (true) {
    int k1 = k0 + 64;
    if (k1 < kendA) loadK(nk, k1);
    loadV(cv, k0);
    proc(aqA, accA, lA, qrA, k0, ck, cv, 0);
    if (k0 < kendB) proc(aqB, accB, lB, qrB, k0, ck, cv, 16);
    if (k1 >= kendA) break;
    k0 = k1; k1 = k0 + 64;
    if (k1 < kendA) loadK(ck, k1);
    loadV(cv, k0);
    proc(aqA, accA, lA, qrA, k0, nk, cv, 0);
    if (k0 < kendB) proc(aqB, accB, lB, qrB, k0, nk, cv, 16);
    if (k1 >= kendA) break;
    k0 = k1;
  }

  // epilogue: reduce l across the 16 lanes of each quad, scale, clip, store
#pragma unroll
  for (int d2 = 1; d2 < 16; d2 <<= 1)
#pragma unroll
    for (int r = 0; r < 4; r++) {
      lA[r] += __shfl_xor(lA[r], d2);
      lB[r] += __shfl_xor(lB[r], d2);
    }
#pragma unroll
  for (int r = 0; r < 4; r++) {
    float rA = 1.f / lA[r], rB = 1.f / lB[r];
#pragma unroll
    for (int dj = 0; dj < 4; dj++) {
      float vA = fminf(fmaxf(accA[dj][r] * rA, -30.f), 30.f);
      float vB = fminf(fmaxf(accB[dj][r] * rB, -30.f), 30.f);
      AOb[(size_t)(qrA + r) * 1024 + dj * 16 + lid] = f2bf(vA);
      AOb[(size_t)(qrB + r) * 1024 + dj * 16 + lid] = f2bf(vB);
    }
  }
}

// ---------------------------------------------------------------------------
extern "C" void kernel_launch(void* const* d_in, const int* in_sizes, int n_in,
                              void* d_out, int out_size, void* d_ws, size_t ws_size,
                              hipStream_t stream) {
  const float* query  = (const float*)d_in[0];
  const float* key_in = (const float*)d_in[1];
  const float* value  = (const float*)d_in[2];
  const float* wq = (const float*)d_in[4];
  const float* bq = (const float*)d_in[5];
  const float* wk = (const float*)d_in[6];
  const float* bk = (const float*)d_in[7];
  const float* wv = (const float*)d_in[8];
  const float* bv = (const float*)d_in[9];
  const float* wo = (const float*)d_in[10];
  const float* bo = (const float*)d_in[11];
  const float* rel = (const float*)d_in[12];

  char* ws = (char*)d_ws;
  unsigned short* Xq = (unsigned short*)(ws);                 // 8.39 MB
  unsigned short* Xk = (unsigned short*)(ws + 8388608);
  unsigned short* Xv = (unsigned short*)(ws + 16777216);
  unsigned short* Wq = (unsigned short*)(ws + 25165824);      // Wq|Wk|Wv|Wo
  unsigned short* Wk = (unsigned short*)(ws + 27262976);      //  contiguous
  unsigned short* Wv = (unsigned short*)(ws + 29360128);      //  -> Wcat
  unsigned short* Wo = (unsigned short*)(ws + 31457280);
  unsigned short* Qr  = (unsigned short*)(ws + 33554432);     // 8.39 MB
  unsigned short* Kr  = (unsigned short*)(ws + 41943040);
  unsigned short* Vtr = (unsigned short*)(ws + 50331648);     // [B,H,D,S]
  unsigned short* AOp = Xq;            // alias: Xq dead after gemm_qkv
  // tab/relt live in d_out scratch (overwritten by gemm_out at the end)
  float* out  = (float*)d_out;
  float* tab  = out;                   // 131072 floats
  float* relt = out + 131072;          // 65520 floats

  dim3 blk(256);
  prep_kernel<<<dim3(8704), blk, 0, stream>>>(
      query, key_in, value, wq, wk, wv, wo,
      Xq, Xk, Xv, Wq, Wk, Wv, Wo, tab, relt, rel);
  gemm_qkv<<<dim3(24, 32), blk, 0, stream>>>(
      Xq, Xk, Xv, Wq /*=Wcat*/, bq, bk, bv, Qr, Kr, Vtr);
  rope_kernel<<<dim3(256, 2), blk, 0, stream>>>(Qr, Kr, tab);
  attn_kernel<<<dim3(2048), dim3(64), 0, stream>>>(Qr, Kr, Vtr, relt, AOp);
  gemm_out<<<dim3(16, 32), blk, 0, stream>>>(AOp, Wo, bo, out);
}